// Round 18
// baseline (361.051 us; speedup 1.0000x reference)
//
#include <hip/hip_runtime.h>
#include <stdint.h>

typedef unsigned short u16;
typedef uint8_t u8;
typedef __attribute__((ext_vector_type(8))) short short8;
typedef __attribute__((ext_vector_type(4))) float f32x4;
typedef __attribute__((ext_vector_type(4))) int i32x4;

#define EPSF 1e-5f
#define LGKM0 asm volatile("s_waitcnt lgkmcnt(0)" ::: "memory")
#define VM0   asm volatile("s_waitcnt vmcnt(0)" ::: "memory")
#define BAR   __builtin_amdgcn_s_barrier()
#define GLL(src, dst) __builtin_amdgcn_global_load_lds(                     \
    (const __attribute__((address_space(1))) void*)(src),                   \
    (__attribute__((address_space(3))) void*)(dst), 16, 0, 0)

__device__ __forceinline__ u16 f2bf(float f) {
  uint32_t u = __float_as_uint(f);
  u += 0x7FFFu + ((u >> 16) & 1u);
  return (u16)(u >> 16);
}
__device__ __forceinline__ u8 sgn8(float y) {
  return y > 0.f ? (u8)1 : (y < 0.f ? (u8)0xFF : (u8)0);
}

// ---------------- BN1 stats (x is NCHW f32: 32,128,64,64) ----------------
__global__ void bn1_stage1(const float* __restrict__ x, float* __restrict__ p1) {
  int c = blockIdx.x >> 2, s = blockIdx.x & 3;
  int tid = threadIdx.x;
  float sum = 0.f, sq = 0.f;
  for (int n = s * 8; n < s * 8 + 8; ++n) {
    const f32x4* bp = (const f32x4*)(x + (((size_t)(n * 128 + c)) << 12));
    #pragma unroll 4
    for (int i = tid; i < 1024; i += 256) {
      f32x4 v = bp[i];
      sum += v[0] + v[1] + v[2] + v[3];
      sq  += v[0]*v[0] + v[1]*v[1] + v[2]*v[2] + v[3]*v[3];
    }
  }
  __shared__ float rs[256], rq[256];
  rs[tid] = sum; rq[tid] = sq; __syncthreads();
  for (int st = 128; st > 0; st >>= 1) {
    if (tid < st) { rs[tid] += rs[tid + st]; rq[tid] += rq[tid + st]; }
    __syncthreads();
  }
  if (tid == 0) { p1[blockIdx.x] = rs[0]; p1[512 + blockIdx.x] = rq[0]; }
}

__global__ void bn1_stage2(const float* __restrict__ p1, const float* __restrict__ g,
                           const float* __restrict__ b, float* __restrict__ sc,
                           float* __restrict__ off) {
  int c = threadIdx.x; // 128 threads
  float s = 0.f, q = 0.f;
  for (int k = 0; k < 4; ++k) { s += p1[c * 4 + k]; q += p1[512 + c * 4 + k]; }
  float mean = s * (1.f / 131072.f);
  float var  = q * (1.f / 131072.f) - mean * mean;
  float is = rsqrtf(var + EPSF);
  float scv = g[c] * is;
  sc[c] = scv;
  off[c] = b[c] - mean * scv;
}

// ---------------- BN2 stage2: reduce per-block partials [2048][256] ----------------
__global__ void bn2_stage2b(const float* __restrict__ pS, const float* __restrict__ pQ,
                            const float* __restrict__ g, const float* __restrict__ bb,
                            float* __restrict__ sc, float* __restrict__ off) {
  int o = blockIdx.x, t = threadIdx.x;
  __shared__ float rs[256], rq[256];
  float s = 0.f, q = 0.f;
  #pragma unroll
  for (int k = 0; k < 8; ++k) {
    size_t j = t + k * 256;
    s += pS[j * 256 + o];
    q += pQ[j * 256 + o];
  }
  rs[t] = s; rq[t] = q; __syncthreads();
  for (int st = 128; st > 0; st >>= 1) {
    if (t < st) { rs[t] += rs[t + st]; rq[t] += rq[t + st]; }
    __syncthreads();
  }
  if (t == 0) {
    float mean = rs[0] * (1.f / 131072.f);
    float var  = rq[0] * (1.f / 131072.f) - mean * mean;
    float is = rsqrtf(var + EPSF);
    float scv = g[o] * is;
    sc[o] = scv;
    off[o] = bb[o] - mean * scv;
  }
}

// ---------------- weight prep ----------------
__device__ __forceinline__ float blk_reduce(float v, float* red) {
  int t = threadIdx.x;
  red[t] = v; __syncthreads();
  for (int st = 128; st > 0; st >>= 1) {
    if (t < st) red[t] += red[t + st];
    __syncthreads();
  }
  float r = red[0]; __syncthreads();
  return r;
}

// Lane-major reg-fragment packs (verified R10/R17).
// i8: byte ((st*4+rg)*64 + (k>>4)*16 + li)*64 + nf*16 + (k&15) holds
//     sign(w[o = rg*64 + nf*16 + li][ch]) for step st.
//     conv1: st = cc*9 + tap, ch = cc*64 + k (18 steps).
//     conv2: st = c4*9 + tap, ch = c4*64 + k (36 steps).
// skip bf16: u16 ((e*4+rg)*64 + kq*16 + li)*64 + (ks*4+nf)*8 + j holds
//     sign(wsk[o][e*64 + ks*32 + kq*8 + j]) * ask/alpha2.
__global__ void prep_weights(const float* __restrict__ w1, const float* __restrict__ w2,
                             const float* __restrict__ wsk, u8* __restrict__ w1r,
                             u8* __restrict__ w2r, u16* __restrict__ wskr,
                             float* __restrict__ alpha1, float* __restrict__ alpha2) {
  int o = blockIdx.x, t = threadIdx.x;
  int rg = o >> 6, nf = (o >> 4) & 3, li = o & 15;
  __shared__ float red[256];
  float s = 0.f;
  for (int j = t; j < 1152; j += 256) s += fabsf(w1[(size_t)o * 1152 + j]);
  float a1 = blk_reduce(s, red) * (1.f / 1152.f);
  if (t == 0) alpha1[o] = a1;
  for (int j = t; j < 1152; j += 256) {
    int st = j >> 6, k = j & 63;
    int cc = st / 9, tap = st % 9;
    int ch = cc * 64 + k;
    size_t idx = ((size_t)((st * 4 + rg) * 64 + (k >> 4) * 16 + li)) * 64 +
                 nf * 16 + (k & 15);
    w1r[idx] = sgn8(w1[(size_t)o * 1152 + ch * 9 + tap]);
  }
  s = 0.f;
  for (int j = t; j < 2304; j += 256) s += fabsf(w2[(size_t)o * 2304 + j]);
  float a2 = blk_reduce(s, red) * (1.f / 2304.f);
  if (t == 0) alpha2[o] = a2;
  for (int j = t; j < 2304; j += 256) {
    int st = j >> 6, k = j & 63;
    int c4 = st / 9, tap = st % 9;
    int ch = c4 * 64 + k;
    size_t idx = ((size_t)((st * 4 + rg) * 64 + (k >> 4) * 16 + li)) * 64 +
                 nf * 16 + (k & 15);
    w2r[idx] = sgn8(w2[(size_t)o * 2304 + ch * 9 + tap]);
  }
  s = 0.f;
  for (int j = t; j < 128; j += 256) s += fabsf(wsk[o * 128 + j]);
  float ask = blk_reduce(s, red) * (1.f / 128.f);
  float ratio = ask / a2;
  for (int j = t; j < 128; j += 256) {
    int e = j >> 6, c = j & 63;
    int ks = c >> 5, kq = (c >> 3) & 3, jj = c & 7;
    float w = wsk[o * 128 + j];
    float v = w > 0.f ? ratio : (w < 0.f ? -ratio : 0.f);
    wskr[((size_t)((e * 4 + rg) * 64 + kq * 16 + li)) * 64 + (ks * 4 + nf) * 8 + jj] =
        f2bf(v);
  }
}

// ---------------- temb = t @ tw^T + tb ----------------
__global__ void temb_k(const float* __restrict__ t, const float* __restrict__ tw,
                       const float* __restrict__ tb, float* __restrict__ temb) {
  int bb = blockIdx.x, o = threadIdx.x;
  __shared__ float tl[512];
  tl[o] = t[bb * 512 + o];
  tl[o + 256] = t[bb * 512 + 256 + o];
  __syncthreads();
  float acc = tb[o];
  #pragma unroll 8
  for (int k = 0; k < 512; ++k) acc += tl[k] * tw[(size_t)o * 512 + k];
  temb[bb * 256 + o] = acc;
}

// ------- border zero: 192 i8 planes of [66][66][64], borders only -------
__global__ void border_zero(u8* __restrict__ Abuf) {
  u8* plane = Abuf + (size_t)blockIdx.x * 278784;
  int tid = threadIdx.x;
  i32x4 z = {};
  for (int idx = tid; idx < 260; idx += 256) {
    int row, px;
    if (idx < 66) { row = 0; px = idx; }
    else if (idx < 132) { row = 65; px = idx - 66; }
    else { int e = idx - 132; row = 1 + (e >> 1); px = (e & 1) * 65; }
    u8* p = plane + (size_t)(row * 66 + px) * 64;
    #pragma unroll
    for (int i = 0; i < 4; ++i) *(i32x4*)(p + i * 16) = z;
  }
}

// -------- binact1: x NCHW -> a1p i8 planes [b*2+cc][66][66][64] + xb bf16 [m][128] --------
__global__ void binact1(const float* __restrict__ x, const float* __restrict__ sc,
                        const float* __restrict__ off, u8* __restrict__ a1p,
                        u16* __restrict__ xb) {
  int b = blockIdx.x >> 6, y = blockIdx.x & 63, tid = threadIdx.x;
  __shared__ u8  ls[64 * 144];
  __shared__ u16 lx[64 * 136];
  int c = tid >> 1, x0 = (tid & 1) * 32;
  const float* src = x + (((size_t)(b * 128 + c)) << 12) + y * 64 + x0;
  float s0 = sc[c], o0 = off[c];
  #pragma unroll
  for (int i = 0; i < 32; i += 4) {
    f32x4 v = *(const f32x4*)(src + i);
    #pragma unroll
    for (int j = 0; j < 4; ++j) {
      int xc = x0 + i + j;
      float yv = s0 * v[j] + o0;
      ls[xc * 144 + c] = sgn8(yv);
      lx[xc * 136 + c] = f2bf(v[j]);
    }
  }
  __syncthreads();
  int xx = tid >> 2, cg = (tid & 3) * 32;
  int cc = cg >> 6, ch0 = cg & 63;
  u8*  pdst = a1p + ((size_t)(b * 2 + cc) * 4356 + (y + 1) * 66 + xx + 1) * 64 + ch0;
  u16* xdst = xb + ((size_t)blockIdx.x * 64 + xx) * 128 + cg;
  *(i32x4*)(pdst)      = *(const i32x4*)&ls[xx * 144 + cg];
  *(i32x4*)(pdst + 16) = *(const i32x4*)&ls[xx * 144 + cg + 16];
  #pragma unroll
  for (int i = 0; i < 32; i += 8)
    *(i32x4*)(xdst + i) = *(const i32x4*)&lx[xx * 136 + cg + i];
}

// -------- binact2: h [m][256] f32 -> a2p i8 planes [b*4+c4][66][66][64] --------
__global__ void binact2(const float* __restrict__ h, const float* __restrict__ sc,
                        const float* __restrict__ off, u8* __restrict__ a2p) {
  int b = blockIdx.x >> 6, y = blockIdx.x & 63, tid = threadIdx.x;
  __shared__ float s_sc[256], s_off[256];
  s_sc[tid] = sc[tid]; s_off[tid] = off[tid];
  __syncthreads();
  const f32x4* src = (const f32x4*)(h + (size_t)blockIdx.x * 16384);
  #pragma unroll 4
  for (int i = tid; i < 4096; i += 256) {
    f32x4 v = src[i];
    int px = i >> 6, c0 = (i & 63) * 4;
    int c4 = c0 >> 6, chm = c0 & 63;
    uint32_t p = (uint32_t)sgn8(s_sc[c0 + 0] * v[0] + s_off[c0 + 0]) |
                 ((uint32_t)sgn8(s_sc[c0 + 1] * v[1] + s_off[c0 + 1]) << 8) |
                 ((uint32_t)sgn8(s_sc[c0 + 2] * v[2] + s_off[c0 + 2]) << 16) |
                 ((uint32_t)sgn8(s_sc[c0 + 3] * v[3] + s_off[c0 + 3]) << 24);
    u8* dst = a2p + ((size_t)(b * 4 + c4) * 4356 + (y + 1) * 66 + px + 1) * 64 + chm;
    *(uint32_t*)dst = p;
  }
}

// ---------------- i8 implicit-GEMM conv: B in registers, window in LDS ----------------
// M=64 (1 image row), N=256, 256 thr = 4 waves (1M x 4N), 16.9 KB LDS.
// A: [3][66][64ch] i8 window per chunk (pre-swizzled-source GLL), read-only.
// B: lane-major register fragments, 2 steps ahead, ping-pong named arrays.
// launch_bounds(256,4): cap arch+acc regs at 128/wave -> 4 waves/SIMD
// (R17 measured 80 arch + 64 acc = 144 -> only 3 waves/SIMD, 29% occupancy;
//  every pipe <35% busy = latency-bound, so residency is the lever).
// Rule #20: all acc/facc indices compile-time.
template <int NCHUNK, bool SKIP, bool ADD_TEMB, bool STATS, bool DIRECT>
__global__ __launch_bounds__(256, 4) void convk(
    const u8* __restrict__ Apl, const u16* __restrict__ xb,
    const u8* __restrict__ wB, const u16* __restrict__ wskr,
    const float* __restrict__ alpha, const float* __restrict__ temb,
    float* __restrict__ outp, float* __restrict__ pS, float* __restrict__ pQ) {
  constexpr int NS = NCHUNK * 9;
  __shared__ u8 smem[16896];
  u8* lA = smem;            // 12672 B window; epilogue scratch reuses smem
  const int tid = threadIdx.x;
  const int lane = tid & 63, wn = tid >> 6;
  const int kq = lane >> 4, li = lane & 15;

  const int bid = blockIdx.x;
  const int tile = (bid & 7) * 256 + (bid >> 3);   // XCD-chunked swizzle (2048%8==0)
  const int m0 = tile * 64;
  const int b = tile >> 6, y = tile & 63;

  // ---- B: lane-major register fragments, 2 steps deep ----
  const i32x4* wlane = (const i32x4*)(wB + ((size_t)wn * 64 + lane) * 64);
  auto loadB = [&](int s, i32x4 (&dst)[4]) {
    const i32x4* src = wlane + (size_t)s * 1024;  // step stride 16384 B
    #pragma unroll
    for (int i = 0; i < 4; ++i) dst[i] = src[i];
  };

  // ---- A window: 792 granules, linear dest + pre-swizzled source ----
  auto winLoad = [&](int c) {
    const u8* gp = Apl + (size_t)(b * NCHUNK + c) * 278784 + (size_t)y * 4224;
    #pragma unroll
    for (int k = 0; k < 3; ++k) {
      int g = tid + k * 256;
      int row = g / 264, rem = g - row * 264;
      int px = rem >> 2, sl = rem & 3;
      const u8* src = gp + (size_t)(row * 66 + px) * 64 + ((sl ^ ((px >> 1) & 3)) << 4);
      u8* dst = lA + (size_t)((tid & ~63) + k * 256) * 16;
      GLL(src, dst);
    }
    if (tid < 24) {
      int rem = 240 + tid;             // row 2, granules 768..791
      int px = rem >> 2, sl = rem & 3;
      const u8* src = gp + (size_t)(2 * 66 + px) * 64 + ((sl ^ ((px >> 1) & 3)) << 4);
      GLL(src, lA + (size_t)768 * 16);
    }
  };

  // ---- A fragment base pointers ----
  const u8* pA[3];
  #pragma unroll
  for (int dx = 0; dx < 3; ++dx)
    pA[dx] = lA + (li + dx) * 64 + ((kq ^ (((li + dx) >> 1) & 3)) << 4);

  i32x4 acc[4][4] = {};

  auto compute = [&](int s, i32x4 (&bcur)[4]) {
    const int tap = s % 9, dy = tap / 3, dx = tap % 3;
    i32x4 av[4];
    #pragma unroll
    for (int f = 0; f < 4; ++f)
      av[f] = *(const i32x4*)(pA[dx] + dy * 4224 + f * 1024);
    __builtin_amdgcn_s_setprio(1);
    #pragma unroll
    for (int mf = 0; mf < 4; ++mf)
      #pragma unroll
      for (int nf = 0; nf < 4; ++nf)
        acc[mf][nf] = __builtin_amdgcn_mfma_i32_16x16x64_i8(
            av[mf], bcur[nf], acc[mf][nf], 0, 0, 0);
    __builtin_amdgcn_s_setprio(0);
  };

  // ---- prologue: window 0 + B(0), B(1) into regs ----
  winLoad(0);
  i32x4 bA[4], bB[4];
  loadB(0, bA);
  loadB(1, bB);
  VM0;                 // window + B regs landed
  BAR;                 // publish window

  // ---- main loop: no manual waits; window drain per 9-step chunk ----
  #pragma unroll
  for (int s = 0; s < NS; ++s) {
    if (NCHUNK > 1 && s > 0 && (s % 9) == 0) {
      LGKM0; BAR;               // all waves done reading old window
      winLoad(s / 9);
      VM0; BAR;                 // new window landed (drains B loads too, ok)
    }
    if ((s & 1) == 0) {
      compute(s, bA);
      if (s + 2 < NS) loadB(s + 2, bA);
    } else {
      compute(s, bB);
      if (s + 2 < NS) loadB(s + 2, bB);
    }
  }

  f32x4 facc[4][4];
  if constexpr (SKIP) {
    #pragma unroll
    for (int mf = 0; mf < 4; ++mf)
      #pragma unroll
      for (int nf = 0; nf < 4; ++nf)
        #pragma unroll
        for (int r = 0; r < 4; ++r)
          facc[mf][nf][r] = (float)acc[mf][nf][r];
    const u8* pAs[2];
    #pragma unroll
    for (int ks = 0; ks < 2; ++ks)
      pAs[ks] = lA + li * 128 + ((((ks << 2) + kq) ^ (li & 7)) << 4);
    LGKM0; BAR;                   // lA free to overwrite
    #pragma unroll
    for (int e = 0; e < 2; ++e) {
      // stage skip-A (xb e-half, pre-swizzled source) into lA: 512 granules
      #pragma unroll
      for (int k = 0; k < 2; ++k) {
        int g = tid + k * 256;
        int m = g >> 3, sl = g & 7;
        const u8* src = (const u8*)xb + (size_t)(m0 + m) * 256 + e * 128 +
                        ((sl ^ (m & 7)) << 4);
        u8* dst = lA + (size_t)((tid & ~63) + k * 256) * 16;
        GLL(src, dst);
      }
      // skip-B lane-major fragments -> regs
      const u16* bbase = wskr + ((size_t)(e * 4 + wn) * 64 + lane) * 64;
      short8 sb[8];
      #pragma unroll
      for (int i = 0; i < 8; ++i) sb[i] = *(const short8*)(bbase + i * 8);
      VM0; BAR;
      #pragma unroll
      for (int ks = 0; ks < 2; ++ks) {
        short8 av[4];
        #pragma unroll
        for (int f = 0; f < 4; ++f) av[f] = *(const short8*)(pAs[ks] + f * 2048);
        __builtin_amdgcn_s_setprio(1);
        #pragma unroll
        for (int mf = 0; mf < 4; ++mf)
          #pragma unroll
          for (int nf = 0; nf < 4; ++nf)
            facc[mf][nf] = __builtin_amdgcn_mfma_f32_16x16x32_bf16(
                av[mf], sb[ks * 4 + nf], facc[mf][nf], 0, 0, 0);
        __builtin_amdgcn_s_setprio(0);
      }
      if (e == 0) { LGKM0; BAR; }
    }
  }

  const int cb = wn * 64 + li;

  if constexpr (STATS) {
    float als[4], tas[4];
    #pragma unroll
    for (int nf = 0; nf < 4; ++nf) {
      int o = cb + nf * 16;
      als[nf] = alpha[o];
      tas[nf] = ADD_TEMB ? temb[b * 256 + o] : 0.f;
    }
    // per-block BN2 partials (deterministic; contiguous [bid][256])
    float ps[4] = {0.f, 0.f, 0.f, 0.f}, pq[4] = {0.f, 0.f, 0.f, 0.f};
    #pragma unroll
    for (int nf = 0; nf < 4; ++nf)
      #pragma unroll
      for (int mf = 0; mf < 4; ++mf)
        #pragma unroll
        for (int r = 0; r < 4; ++r) {
          float v = (float)acc[mf][nf][r] * als[nf] + tas[nf];
          ps[nf] += v; pq[nf] += v * v;
        }
    #pragma unroll
    for (int nf = 0; nf < 4; ++nf) {
      ps[nf] += __shfl_xor(ps[nf], 16); ps[nf] += __shfl_xor(ps[nf], 32);
      pq[nf] += __shfl_xor(pq[nf], 16); pq[nf] += __shfl_xor(pq[nf], 32);
    }
    if (lane < 16) {
      #pragma unroll
      for (int nf = 0; nf < 4; ++nf) {
        pS[(size_t)bid * 256 + wn * 64 + nf * 16 + lane] = ps[nf];
        pQ[(size_t)bid * 256 + wn * 64 + nf * 16 + lane] = pq[nf];
      }
    }
    __syncthreads();      // all waves done with window before reuse as scratch
    // restage h tile through LDS in four 16-row passes [16][256] f32 (16 KB).
    // FULLY UNROLLED so acc indices stay compile-time (rule #20): pass p == mf.
    float* ld = (float*)smem;
    const int c3 = li & 3;
    #pragma unroll
    for (int p = 0; p < 4; ++p) {
      #pragma unroll
      for (int nf = 0; nf < 4; ++nf) {
        int colg0 = (cb >> 2) + nf * 4;
        #pragma unroll
        for (int r = 0; r < 4; ++r) {
          int rloc = 4 * kq + r;
          float v = (float)acc[p][nf][r] * als[nf] + tas[nf];
          ld[rloc * 256 + ((colg0 ^ kq) << 2) + c3] = v;
        }
      }
      __syncthreads();
      #pragma unroll
      for (int it = 0; it < 4; ++it) {
        int flat = tid + it * 256;
        int row = flat >> 6, c4 = flat & 63;
        int c4p = c4 ^ ((row >> 2) & 3);
        f32x4 v = *(const f32x4*)&ld[row * 256 + c4p * 4];
        *(f32x4*)(outp + (size_t)(m0 + p * 16 + row) * 256 + c4 * 4) = v;
      }
      __syncthreads();
    }
  } else if constexpr (DIRECT) {
    // NCHW transpose epilogue: [64 m][65] f32 tile per 64-ch quarter
    float* tb2 = (float*)smem;
    float* obase = outp + (((size_t)(b * 256)) << 12) + (m0 & 4095);
    __syncthreads();
    #pragma unroll
    for (int c4 = 0; c4 < 4; ++c4) {
      if (wn == c4) {
        #pragma unroll
        for (int nf = 0; nf < 4; ++nf) {
          float al = alpha[c4 * 64 + nf * 16 + li];
          #pragma unroll
          for (int mf = 0; mf < 4; ++mf) {
            int cs = (li + nf * 16) ^ ((mf >> 1) & 3);
            #pragma unroll
            for (int r = 0; r < 4; ++r)
              tb2[(mf * 16 + 4 * kq + r) * 65 + cs] = facc[mf][nf][r] * al;
          }
        }
      }
      __syncthreads();
      #pragma unroll
      for (int it = 0; it < 4; ++it) {
        int flat = tid + it * 256;
        int ch = flat >> 4, mg = flat & 15;
        int chs = ch ^ ((mg >> 3) & 3);
        f32x4 v;
        #pragma unroll
        for (int e = 0; e < 4; ++e) v[e] = tb2[(mg * 4 + e) * 65 + chs];
        *(f32x4*)(obase + (((size_t)(c4 * 64 + ch)) << 12) + mg * 4) = v;
      }
      __syncthreads();
    }
  }
}

extern "C" void kernel_launch(void* const* d_in, const int* in_sizes, int n_in,
                              void* d_out, int out_size, void* d_ws, size_t ws_size,
                              hipStream_t stream) {
  const float* x      = (const float*)d_in[0];
  const float* t      = (const float*)d_in[1];
  const float* w1     = (const float*)d_in[2];
  const float* w2     = (const float*)d_in[3];
  const float* wskip  = (const float*)d_in[4];
  const float* gamma1 = (const float*)d_in[5];
  const float* beta1  = (const float*)d_in[6];
  const float* gamma2 = (const float*)d_in[7];
  const float* beta2  = (const float*)d_in[8];
  const float* tw     = (const float*)d_in[9];
  const float* tb     = (const float*)d_in[10];
  float* out = (float*)d_out;

  uint8_t* base = (uint8_t*)d_ws;
  size_t off = 0;
  auto alloc = [&](size_t bytes) {
    void* p = base + off;
    off += (bytes + 255) & ~(size_t)255;
    return p;
  };
  // 192 i8 planes of [66][66][64]: first 64 = a1p (32b x 2), next 128 = a2p (32b x 4)
  u8* Abuf     = (u8*)alloc((size_t)192 * 278784);
  u8* a1p      = Abuf;
  u8* a2p      = Abuf + (size_t)64 * 278784;
  u16* xb      = (u16*)alloc((size_t)131072 * 128 * 2);
  float* h     = (float*)alloc((size_t)131072 * 256 * 4);
  u8* w1r      = (u8*)alloc((size_t)18 * 16384);
  u8* w2r      = (u8*)alloc((size_t)36 * 16384);
  u16* wskr    = (u16*)alloc((size_t)2 * 16384 * 2);
  float* temb  = (float*)alloc(32 * 256 * 4);
  float* alpha1 = (float*)alloc(256 * 4);
  float* alpha2 = (float*)alloc(256 * 4);
  float* p1    = (float*)alloc(1024 * 4);
  float* pS    = (float*)alloc((size_t)2048 * 256 * 4);
  float* pQ    = (float*)alloc((size_t)2048 * 256 * 4);
  float* sc1   = (float*)alloc(128 * 4);
  float* off1  = (float*)alloc(128 * 4);
  float* sc2   = (float*)alloc(256 * 4);
  float* off2  = (float*)alloc(256 * 4);

  border_zero<<<192, 256, 0, stream>>>(Abuf);

  bn1_stage1<<<512, 256, 0, stream>>>(x, p1);
  bn1_stage2<<<1, 128, 0, stream>>>(p1, gamma1, beta1, sc1, off1);
  prep_weights<<<256, 256, 0, stream>>>(w1, w2, wskip, w1r, w2r, wskr, alpha1, alpha2);
  temb_k<<<32, 256, 0, stream>>>(t, tw, tb, temb);
  binact1<<<2048, 256, 0, stream>>>(x, sc1, off1, a1p, xb);

  // conv1: i8, 2 chunks, writes h + BN2 per-block partials
  convk<2, false, true, true, false><<<2048, 256, 0, stream>>>(
      a1p, xb, w1r, (const u16*)nullptr, alpha1, temb, h, pS, pQ);

  bn2_stage2b<<<256, 256, 0, stream>>>(pS, pQ, gamma2, beta2, sc2, off2);
  binact2<<<2048, 256, 0, stream>>>(h, sc2, off2, a2p);

  // conv2: i8, 4 chunks + bf16 skip tail, direct NCHW output
  convk<4, true, false, false, true><<<2048, 256, 0, stream>>>(
      a2p, xb, w2r, wskr, alpha2, (const float*)nullptr, out,
      (float*)nullptr, (float*)nullptr);

  (void)in_sizes; (void)n_in; (void)out_size; (void)ws_size;
}

// Round 19
// 290.023 us; speedup vs baseline: 1.2449x; 1.2449x over previous
//
#include <hip/hip_runtime.h>
#include <stdint.h>

typedef unsigned short u16;
typedef uint8_t u8;
typedef __attribute__((ext_vector_type(8))) short short8;
typedef __attribute__((ext_vector_type(4))) float f32x4;
typedef __attribute__((ext_vector_type(4))) int i32x4;

#define EPSF 1e-5f
#define LGKM0 asm volatile("s_waitcnt lgkmcnt(0)" ::: "memory")
#define VM0   asm volatile("s_waitcnt vmcnt(0)" ::: "memory")
#define VM2   asm volatile("s_waitcnt vmcnt(2)" ::: "memory")
#define BAR   __builtin_amdgcn_s_barrier()
#define GLL(src, dst) __builtin_amdgcn_global_load_lds(                     \
    (const __attribute__((address_space(1))) void*)(src),                   \
    (__attribute__((address_space(3))) void*)(dst), 16, 0, 0)

__device__ __forceinline__ u16 f2bf(float f) {
  uint32_t u = __float_as_uint(f);
  u += 0x7FFFu + ((u >> 16) & 1u);
  return (u16)(u >> 16);
}
__device__ __forceinline__ u8 sgn8(float y) {
  return y > 0.f ? (u8)1 : (y < 0.f ? (u8)0xFF : (u8)0);
}

// ---------------- BN1 stats (x is NCHW f32: 32,128,64,64) ----------------
__global__ void bn1_stage1(const float* __restrict__ x, float* __restrict__ p1) {
  int c = blockIdx.x >> 2, s = blockIdx.x & 3;
  int tid = threadIdx.x;
  float sum = 0.f, sq = 0.f;
  for (int n = s * 8; n < s * 8 + 8; ++n) {
    const f32x4* bp = (const f32x4*)(x + (((size_t)(n * 128 + c)) << 12));
    #pragma unroll 4
    for (int i = tid; i < 1024; i += 256) {
      f32x4 v = bp[i];
      sum += v[0] + v[1] + v[2] + v[3];
      sq  += v[0]*v[0] + v[1]*v[1] + v[2]*v[2] + v[3]*v[3];
    }
  }
  __shared__ float rs[256], rq[256];
  rs[tid] = sum; rq[tid] = sq; __syncthreads();
  for (int st = 128; st > 0; st >>= 1) {
    if (tid < st) { rs[tid] += rs[tid + st]; rq[tid] += rq[tid + st]; }
    __syncthreads();
  }
  if (tid == 0) { p1[blockIdx.x] = rs[0]; p1[512 + blockIdx.x] = rq[0]; }
}

__global__ void bn1_stage2(const float* __restrict__ p1, const float* __restrict__ g,
                           const float* __restrict__ b, float* __restrict__ sc,
                           float* __restrict__ off) {
  int c = threadIdx.x; // 128 threads
  float s = 0.f, q = 0.f;
  for (int k = 0; k < 4; ++k) { s += p1[c * 4 + k]; q += p1[512 + c * 4 + k]; }
  float mean = s * (1.f / 131072.f);
  float var  = q * (1.f / 131072.f) - mean * mean;
  float is = rsqrtf(var + EPSF);
  float scv = g[c] * is;
  sc[c] = scv;
  off[c] = b[c] - mean * scv;
}

// ---------------- BN2 stage2: reduce per-block partials [2048][256] ----------------
__global__ void bn2_stage2b(const float* __restrict__ pS, const float* __restrict__ pQ,
                            const float* __restrict__ g, const float* __restrict__ bb,
                            float* __restrict__ sc, float* __restrict__ off) {
  int o = blockIdx.x, t = threadIdx.x;
  __shared__ float rs[256], rq[256];
  float s = 0.f, q = 0.f;
  #pragma unroll
  for (int k = 0; k < 8; ++k) {
    size_t j = t + k * 256;
    s += pS[j * 256 + o];
    q += pQ[j * 256 + o];
  }
  rs[t] = s; rq[t] = q; __syncthreads();
  for (int st = 128; st > 0; st >>= 1) {
    if (t < st) { rs[t] += rs[t + st]; rq[t] += rq[t + st]; }
    __syncthreads();
  }
  if (t == 0) {
    float mean = rs[0] * (1.f / 131072.f);
    float var  = rq[0] * (1.f / 131072.f) - mean * mean;
    float is = rsqrtf(var + EPSF);
    float scv = g[o] * is;
    sc[o] = scv;
    off[o] = bb[o] - mean * scv;
  }
}

// ---------------- weight prep ----------------
__device__ __forceinline__ float blk_reduce(float v, float* red) {
  int t = threadIdx.x;
  red[t] = v; __syncthreads();
  for (int st = 128; st > 0; st >>= 1) {
    if (t < st) red[t] += red[t + st];
    __syncthreads();
  }
  float r = red[0]; __syncthreads();
  return r;
}

// i8 step blocks, 8 wave-private regions of 2048B:
// byte = (st*8 + rg8)*2048 + ((ol<<2) + ((k>>4) ^ ((ol>>1)&3)))*16 + (k&15)
// where o = rg8*32 + ol.  conv1: st = cc*9+tap, ch = cc*64+k (18 steps).
// conv2: st = c4*9+tap, ch = c4*64+k (36 steps).
// skip bf16 lane-major per region: u16 ((e*8+rg8)*64 + kq*16+li)*32 + (ks*2+nf)*8 + j
// holds sign(wsk[o = rg8*32+nf*16+li][e*64 + ks*32 + kq*8 + j]) * ask/alpha2.
__global__ void prep_weights(const float* __restrict__ w1, const float* __restrict__ w2,
                             const float* __restrict__ wsk, u8* __restrict__ w1s,
                             u8* __restrict__ w2s, u16* __restrict__ wskr,
                             float* __restrict__ alpha1, float* __restrict__ alpha2) {
  int o = blockIdx.x, t = threadIdx.x;
  int rg8 = o >> 5, ol = o & 31;
  __shared__ float red[256];
  float s = 0.f;
  for (int j = t; j < 1152; j += 256) s += fabsf(w1[(size_t)o * 1152 + j]);
  float a1 = blk_reduce(s, red) * (1.f / 1152.f);
  if (t == 0) alpha1[o] = a1;
  for (int j = t; j < 1152; j += 256) {
    int st = j >> 6, k = j & 63;
    int cc = st / 9, tap = st % 9;
    int ch = cc * 64 + k;
    size_t idx = (size_t)(st * 8 + rg8) * 2048 +
                 ((ol << 2) + ((k >> 4) ^ ((ol >> 1) & 3))) * 16 + (k & 15);
    w1s[idx] = sgn8(w1[(size_t)o * 1152 + ch * 9 + tap]);
  }
  s = 0.f;
  for (int j = t; j < 2304; j += 256) s += fabsf(w2[(size_t)o * 2304 + j]);
  float a2 = blk_reduce(s, red) * (1.f / 2304.f);
  if (t == 0) alpha2[o] = a2;
  for (int j = t; j < 2304; j += 256) {
    int st = j >> 6, k = j & 63;
    int c4 = st / 9, tap = st % 9;
    int ch = c4 * 64 + k;
    size_t idx = (size_t)(st * 8 + rg8) * 2048 +
                 ((ol << 2) + ((k >> 4) ^ ((ol >> 1) & 3))) * 16 + (k & 15);
    w2s[idx] = sgn8(w2[(size_t)o * 2304 + ch * 9 + tap]);
  }
  s = 0.f;
  for (int j = t; j < 128; j += 256) s += fabsf(wsk[o * 128 + j]);
  float ask = blk_reduce(s, red) * (1.f / 128.f);
  float ratio = ask / a2;
  int nf = (o >> 4) & 1, li = o & 15;
  for (int j = t; j < 128; j += 256) {
    int e = j >> 6, c = j & 63;
    int ks = c >> 5, kq = (c >> 3) & 3, jj = c & 7;
    float w = wsk[o * 128 + j];
    float v = w > 0.f ? ratio : (w < 0.f ? -ratio : 0.f);
    wskr[((size_t)((e * 8 + rg8) * 64 + kq * 16 + li)) * 32 + (ks * 2 + nf) * 8 + jj] =
        f2bf(v);
  }
}

// ---------------- temb = t @ tw^T + tb ----------------
__global__ void temb_k(const float* __restrict__ t, const float* __restrict__ tw,
                       const float* __restrict__ tb, float* __restrict__ temb) {
  int bb = blockIdx.x, o = threadIdx.x;
  __shared__ float tl[512];
  tl[o] = t[bb * 512 + o];
  tl[o + 256] = t[bb * 512 + 256 + o];
  __syncthreads();
  float acc = tb[o];
  #pragma unroll 8
  for (int k = 0; k < 512; ++k) acc += tl[k] * tw[(size_t)o * 512 + k];
  temb[bb * 256 + o] = acc;
}

// ------- border zero: 192 i8 planes of [66][66][64], borders only -------
__global__ void border_zero(u8* __restrict__ Abuf) {
  u8* plane = Abuf + (size_t)blockIdx.x * 278784;
  int tid = threadIdx.x;
  i32x4 z = {};
  for (int idx = tid; idx < 260; idx += 256) {
    int row, px;
    if (idx < 66) { row = 0; px = idx; }
    else if (idx < 132) { row = 65; px = idx - 66; }
    else { int e = idx - 132; row = 1 + (e >> 1); px = (e & 1) * 65; }
    u8* p = plane + (size_t)(row * 66 + px) * 64;
    #pragma unroll
    for (int i = 0; i < 4; ++i) *(i32x4*)(p + i * 16) = z;
  }
}

// -------- binact1: x NCHW -> a1p i8 planes [b*2+cc][66][66][64] + xb bf16 [m][128] --------
__global__ void binact1(const float* __restrict__ x, const float* __restrict__ sc,
                        const float* __restrict__ off, u8* __restrict__ a1p,
                        u16* __restrict__ xb) {
  int b = blockIdx.x >> 6, y = blockIdx.x & 63, tid = threadIdx.x;
  __shared__ u8  ls[64 * 144];
  __shared__ u16 lx[64 * 136];
  int c = tid >> 1, x0 = (tid & 1) * 32;
  const float* src = x + (((size_t)(b * 128 + c)) << 12) + y * 64 + x0;
  float s0 = sc[c], o0 = off[c];
  #pragma unroll
  for (int i = 0; i < 32; i += 4) {
    f32x4 v = *(const f32x4*)(src + i);
    #pragma unroll
    for (int j = 0; j < 4; ++j) {
      int xc = x0 + i + j;
      float yv = s0 * v[j] + o0;
      ls[xc * 144 + c] = sgn8(yv);
      lx[xc * 136 + c] = f2bf(v[j]);
    }
  }
  __syncthreads();
  int xx = tid >> 2, cg = (tid & 3) * 32;
  int cc = cg >> 6, ch0 = cg & 63;
  u8*  pdst = a1p + ((size_t)(b * 2 + cc) * 4356 + (y + 1) * 66 + xx + 1) * 64 + ch0;
  u16* xdst = xb + ((size_t)blockIdx.x * 64 + xx) * 128 + cg;
  *(i32x4*)(pdst)      = *(const i32x4*)&ls[xx * 144 + cg];
  *(i32x4*)(pdst + 16) = *(const i32x4*)&ls[xx * 144 + cg + 16];
  #pragma unroll
  for (int i = 0; i < 32; i += 8)
    *(i32x4*)(xdst + i) = *(const i32x4*)&lx[xx * 136 + cg + i];
}

// -------- binact2: h [m][256] f32 -> a2p i8 planes [b*4+c4][66][66][64] --------
__global__ void binact2(const float* __restrict__ h, const float* __restrict__ sc,
                        const float* __restrict__ off, u8* __restrict__ a2p) {
  int b = blockIdx.x >> 6, y = blockIdx.x & 63, tid = threadIdx.x;
  __shared__ float s_sc[256], s_off[256];
  s_sc[tid] = sc[tid]; s_off[tid] = off[tid];
  __syncthreads();
  const f32x4* src = (const f32x4*)(h + (size_t)blockIdx.x * 16384);
  #pragma unroll 4
  for (int i = tid; i < 4096; i += 256) {
    f32x4 v = src[i];
    int px = i >> 6, c0 = (i & 63) * 4;
    int c4 = c0 >> 6, chm = c0 & 63;
    uint32_t p = (uint32_t)sgn8(s_sc[c0 + 0] * v[0] + s_off[c0 + 0]) |
                 ((uint32_t)sgn8(s_sc[c0 + 1] * v[1] + s_off[c0 + 1]) << 8) |
                 ((uint32_t)sgn8(s_sc[c0 + 2] * v[2] + s_off[c0 + 2]) << 16) |
                 ((uint32_t)sgn8(s_sc[c0 + 3] * v[3] + s_off[c0 + 3]) << 24);
    u8* dst = a2p + ((size_t)(b * 4 + c4) * 4356 + (y + 1) * 66 + px + 1) * 64 + chm;
    *(uint32_t*)dst = p;
  }
}

// ---------------- i8 implicit-GEMM conv: 8 waves, 32-col wave-private B ----------------
// M=64 (1 image row), N=256, 512 thr = 8 waves (each owns 32 output cols),
// 45.4 KB LDS -> 2 blocks/CU = 16 waves/CU. Per-wave acc[4][2] = 32 AGPRs
// (half of R14) so arch+acc ~= 100 regs -> 4 waves/SIMD without spill.
// A: [3][66][64ch] i8 window per chunk (pre-swizzled-source GLL), read-only.
// B: 8 wave-private 2048B regions per step slot; GLL 2 steps deep, counted
//    vmcnt(2); no per-step barriers (all B hazards intra-wave).
// Window drain once per 9-step chunk. Rule #20: all acc indices compile-time.
template <int NCHUNK, bool SKIP, bool ADD_TEMB, bool STATS, bool DIRECT>
__global__ __launch_bounds__(512, 2) void convk(
    const u8* __restrict__ Apl, const u16* __restrict__ xb,
    const u8* __restrict__ wS, const u16* __restrict__ wskr,
    const float* __restrict__ alpha, const float* __restrict__ temb,
    float* __restrict__ outp, float* __restrict__ pS, float* __restrict__ pQ) {
  constexpr int NS = NCHUNK * 9;
  __shared__ u8 smem[45440];
  u8* lA = smem;            // 12672 B window
  u8* lB = smem + 12672;    // 2 x 16384 B (8 regions x 2048B each)
  const int tid = threadIdx.x;
  const int lane = tid & 63, wn = tid >> 6;      // wn in 0..7
  const int kq = lane >> 4, li = lane & 15;

  const int bid = blockIdx.x;
  const int tile = (bid & 7) * 256 + (bid >> 3);   // XCD-chunked swizzle (2048%8==0)
  const int m0 = tile * 64;
  const int b = tile >> 6, y = tile & 63;

  // ---- B: wave-private 2048B region, 2 GLLs per step ----
  auto issueB = [&](int s) {
    const u8* src = wS + (size_t)s * 16384 + wn * 2048 + lane * 16;
    u8* dst = lB + (s & 1) * 16384 + wn * 2048;
    GLL(src, dst);
    GLL(src + 1024, dst + 1024);
  };

  // ---- A window: 792 granules, linear dest + pre-swizzled source ----
  auto winLoad = [&](int c) {
    const u8* gp = Apl + (size_t)(b * NCHUNK + c) * 278784 + (size_t)y * 4224;
    {
      int g = tid;
      int row = g / 264, rem = g - row * 264;
      int px = rem >> 2, sl = rem & 3;
      const u8* src = gp + (size_t)(row * 66 + px) * 64 + ((sl ^ ((px >> 1) & 3)) << 4);
      u8* dst = lA + (size_t)(tid & ~63) * 16;
      GLL(src, dst);
    }
    if (tid < 280) {
      int g = 512 + tid;
      int row = g / 264, rem = g - row * 264;
      int px = rem >> 2, sl = rem & 3;
      const u8* src = gp + (size_t)(row * 66 + px) * 64 + ((sl ^ ((px >> 1) & 3)) << 4);
      u8* dst = lA + (size_t)((512 + (tid & ~63)) & ~63) * 16;
      GLL(src, dst);
    }
  };

  // ---- fragment base pointers ----
  const u8* pA[3];
  #pragma unroll
  for (int dx = 0; dx < 3; ++dx)
    pA[dx] = lA + (li + dx) * 64 + ((kq ^ (((li + dx) >> 1) & 3)) << 4);
  const u8* pB = lB + wn * 2048 + li * 64 + ((kq ^ ((li >> 1) & 3)) << 4);

  i32x4 acc[4][2] = {};

  auto compute = [&](int tap, int buf) {
    const int dy = tap / 3, dx = tap % 3;
    i32x4 av[4], bv[2];
    #pragma unroll
    for (int f = 0; f < 4; ++f)
      av[f] = *(const i32x4*)(pA[dx] + dy * 4224 + f * 1024);
    #pragma unroll
    for (int nf = 0; nf < 2; ++nf)
      bv[nf] = *(const i32x4*)(pB + buf * 16384 + nf * 1024);
    __builtin_amdgcn_s_setprio(1);
    #pragma unroll
    for (int mf = 0; mf < 4; ++mf)
      #pragma unroll
      for (int nf = 0; nf < 2; ++nf)
        acc[mf][nf] = __builtin_amdgcn_mfma_i32_16x16x64_i8(
            av[mf], bv[nf], acc[mf][nf], 0, 0, 0);
    __builtin_amdgcn_s_setprio(0);
  };

  // ---- prologue: window 0 + B(0), B(1) ----
  winLoad(0);
  issueB(0);
  issueB(1);
  VM0;                 // everything landed
  BAR;                 // publish window

  // ---- main loop: barrier-free; window drain once per 9-step chunk ----
  #pragma unroll
  for (int s = 0; s < NS; ++s) {
    if (NCHUNK > 1 && s > 0 && (s % 9) == 0) {
      LGKM0; BAR;               // all waves done reading old window
      winLoad(s / 9);
      VM0; BAR;                 // new window (and all B in flight) landed
    }
    if (s + 2 < NS) { VM2; } else { VM0; }   // B(s) landed
    compute(s % 9, s & 1);
    LGKM0;                                    // my reads of lB[s&1] complete
    if (s + 2 < NS) issueB(s + 2);            // wave-private slot rewrite
  }

  f32x4 facc[4][2];
  if constexpr (SKIP) {
    #pragma unroll
    for (int mf = 0; mf < 4; ++mf)
      #pragma unroll
      for (int nf = 0; nf < 2; ++nf)
        #pragma unroll
        for (int r = 0; r < 4; ++r)
          facc[mf][nf][r] = (float)acc[mf][nf][r];
    const u8* pAs[2];
    #pragma unroll
    for (int ks = 0; ks < 2; ++ks)
      pAs[ks] = lA + li * 128 + ((((ks << 2) + kq) ^ (li & 7)) << 4);
    LGKM0; BAR;                   // lA free to overwrite
    #pragma unroll
    for (int e = 0; e < 2; ++e) {
      // stage skip-A (xb e-half, pre-swizzled source) into lA: 512 granules
      {
        int g = tid;
        int m = g >> 3, sl = g & 7;
        const u8* src = (const u8*)xb + (size_t)(m0 + m) * 256 + e * 128 +
                        ((sl ^ (m & 7)) << 4);
        u8* dst = lA + (size_t)(tid & ~63) * 16;
        GLL(src, dst);
      }
      // skip-B lane-major fragments -> regs (4 x short8 per lane)
      const u16* bbase = wskr + ((size_t)((e * 8 + wn) * 64) + lane) * 32;
      short8 sb[4];
      #pragma unroll
      for (int i = 0; i < 4; ++i) sb[i] = *(const short8*)(bbase + i * 8);
      VM0; BAR;
      #pragma unroll
      for (int ks = 0; ks < 2; ++ks) {
        short8 av[4];
        #pragma unroll
        for (int f = 0; f < 4; ++f) av[f] = *(const short8*)(pAs[ks] + f * 2048);
        __builtin_amdgcn_s_setprio(1);
        #pragma unroll
        for (int mf = 0; mf < 4; ++mf)
          #pragma unroll
          for (int nf = 0; nf < 2; ++nf)
            facc[mf][nf] = __builtin_amdgcn_mfma_f32_16x16x32_bf16(
                av[mf], sb[ks * 2 + nf], facc[mf][nf], 0, 0, 0);
        __builtin_amdgcn_s_setprio(0);
      }
      if (e == 0) { LGKM0; BAR; }
    }
  }

  const int cb = wn * 32 + li;

  if constexpr (STATS) {
    float als[2], tas[2];
    #pragma unroll
    for (int nf = 0; nf < 2; ++nf) {
      int o = cb + nf * 16;
      als[nf] = alpha[o];
      tas[nf] = ADD_TEMB ? temb[b * 256 + o] : 0.f;
    }
    // per-block BN2 partials (deterministic; contiguous [bid][256])
    float ps[2] = {0.f, 0.f}, pq[2] = {0.f, 0.f};
    #pragma unroll
    for (int nf = 0; nf < 2; ++nf)
      #pragma unroll
      for (int mf = 0; mf < 4; ++mf)
        #pragma unroll
        for (int r = 0; r < 4; ++r) {
          float v = (float)acc[mf][nf][r] * als[nf] + tas[nf];
          ps[nf] += v; pq[nf] += v * v;
        }
    #pragma unroll
    for (int nf = 0; nf < 2; ++nf) {
      ps[nf] += __shfl_xor(ps[nf], 16); ps[nf] += __shfl_xor(ps[nf], 32);
      pq[nf] += __shfl_xor(pq[nf], 16); pq[nf] += __shfl_xor(pq[nf], 32);
    }
    if (lane < 16) {
      #pragma unroll
      for (int nf = 0; nf < 2; ++nf) {
        pS[(size_t)bid * 256 + wn * 32 + nf * 16 + lane] = ps[nf];
        pQ[(size_t)bid * 256 + wn * 32 + nf * 16 + lane] = pq[nf];
      }
    }
    __syncthreads();      // all waves done with window before reuse as scratch
    // restage h tile through LDS in four 16-row passes [16][256] f32 (16 KB).
    // FULLY UNROLLED (rule #20): pass p == mf.
    float* ld = (float*)smem;
    const int c3 = li & 3;
    #pragma unroll
    for (int p = 0; p < 4; ++p) {
      #pragma unroll
      for (int nf = 0; nf < 2; ++nf) {
        int colg0 = (cb >> 2) + nf * 4;
        #pragma unroll
        for (int r = 0; r < 4; ++r) {
          int rloc = 4 * kq + r;
          float v = (float)acc[p][nf][r] * als[nf] + tas[nf];
          ld[rloc * 256 + ((colg0 ^ kq) << 2) + c3] = v;
        }
      }
      __syncthreads();
      #pragma unroll
      for (int it = 0; it < 2; ++it) {
        int flat = tid + it * 512;
        int row = flat >> 6, c4 = flat & 63;
        int c4p = c4 ^ ((row >> 2) & 3);
        f32x4 v = *(const f32x4*)&ld[row * 256 + c4p * 4];
        *(f32x4*)(outp + (size_t)(m0 + p * 16 + row) * 256 + c4 * 4) = v;
      }
      __syncthreads();
    }
  } else if constexpr (DIRECT) {
    // NCHW transpose epilogue: [64 m][65] f32 tile per 64-ch quarter.
    // Quarter c4 is written by waves 2*c4 and 2*c4+1 (32 cols each).
    float* tb2 = (float*)smem;
    float* obase = outp + (((size_t)(b * 256)) << 12) + (m0 & 4095);
    __syncthreads();
    #pragma unroll
    for (int c4 = 0; c4 < 4; ++c4) {
      if ((wn >> 1) == c4) {
        #pragma unroll
        for (int nf = 0; nf < 2; ++nf) {
          int cq = (wn & 1) * 32 + nf * 16 + li;
          float al = alpha[c4 * 64 + cq];
          #pragma unroll
          for (int mf = 0; mf < 4; ++mf) {
            int cs = cq ^ ((mf >> 1) & 3);
            #pragma unroll
            for (int r = 0; r < 4; ++r)
              tb2[(mf * 16 + 4 * kq + r) * 65 + cs] = facc[mf][nf][r] * al;
          }
        }
      }
      __syncthreads();
      #pragma unroll
      for (int it = 0; it < 2; ++it) {
        int flat = tid + it * 512;
        int ch = flat >> 4, mg = flat & 15;
        int chs = ch ^ ((mg >> 3) & 3);
        f32x4 v;
        #pragma unroll
        for (int e = 0; e < 4; ++e) v[e] = tb2[(mg * 4 + e) * 65 + chs];
        *(f32x4*)(obase + (((size_t)(c4 * 64 + ch)) << 12) + mg * 4) = v;
      }
      __syncthreads();
    }
  }
}

extern "C" void kernel_launch(void* const* d_in, const int* in_sizes, int n_in,
                              void* d_out, int out_size, void* d_ws, size_t ws_size,
                              hipStream_t stream) {
  const float* x      = (const float*)d_in[0];
  const float* t      = (const float*)d_in[1];
  const float* w1     = (const float*)d_in[2];
  const float* w2     = (const float*)d_in[3];
  const float* wskip  = (const float*)d_in[4];
  const float* gamma1 = (const float*)d_in[5];
  const float* beta1  = (const float*)d_in[6];
  const float* gamma2 = (const float*)d_in[7];
  const float* beta2  = (const float*)d_in[8];
  const float* tw     = (const float*)d_in[9];
  const float* tb     = (const float*)d_in[10];
  float* out = (float*)d_out;

  uint8_t* base = (uint8_t*)d_ws;
  size_t off = 0;
  auto alloc = [&](size_t bytes) {
    void* p = base + off;
    off += (bytes + 255) & ~(size_t)255;
    return p;
  };
  // 192 i8 planes of [66][66][64]: first 64 = a1p (32b x 2), next 128 = a2p (32b x 4)
  u8* Abuf     = (u8*)alloc((size_t)192 * 278784);
  u8* a1p      = Abuf;
  u8* a2p      = Abuf + (size_t)64 * 278784;
  u16* xb      = (u16*)alloc((size_t)131072 * 128 * 2);
  float* h     = (float*)alloc((size_t)131072 * 256 * 4);
  u8* w1s      = (u8*)alloc((size_t)18 * 16384);
  u8* w2s      = (u8*)alloc((size_t)36 * 16384);
  u16* wskr    = (u16*)alloc((size_t)2 * 8 * 4096);
  float* temb  = (float*)alloc(32 * 256 * 4);
  float* alpha1 = (float*)alloc(256 * 4);
  float* alpha2 = (float*)alloc(256 * 4);
  float* p1    = (float*)alloc(1024 * 4);
  float* pS    = (float*)alloc((size_t)2048 * 256 * 4);
  float* pQ    = (float*)alloc((size_t)2048 * 256 * 4);
  float* sc1   = (float*)alloc(128 * 4);
  float* off1  = (float*)alloc(128 * 4);
  float* sc2   = (float*)alloc(256 * 4);
  float* off2  = (float*)alloc(256 * 4);

  border_zero<<<192, 256, 0, stream>>>(Abuf);

  bn1_stage1<<<512, 256, 0, stream>>>(x, p1);
  bn1_stage2<<<1, 128, 0, stream>>>(p1, gamma1, beta1, sc1, off1);
  prep_weights<<<256, 256, 0, stream>>>(w1, w2, wskip, w1s, w2s, wskr, alpha1, alpha2);
  temb_k<<<32, 256, 0, stream>>>(t, tw, tb, temb);
  binact1<<<2048, 256, 0, stream>>>(x, sc1, off1, a1p, xb);

  // conv1: i8, 2 chunks, writes h + BN2 per-block partials
  convk<2, false, true, true, false><<<2048, 512, 0, stream>>>(
      a1p, xb, w1s, (const u16*)nullptr, alpha1, temb, h, pS, pQ);

  bn2_stage2b<<<256, 256, 0, stream>>>(pS, pQ, gamma2, beta2, sc2, off2);
  binact2<<<2048, 256, 0, stream>>>(h, sc2, off2, a2p);

  // conv2: i8, 4 chunks + bf16 skip tail, direct NCHW output
  convk<4, true, false, false, true><<<2048, 512, 0, stream>>>(
      a2p, xb, w2s, wskr, alpha2, (const float*)nullptr, out,
      (float*)nullptr, (float*)nullptr);

  (void)in_sizes; (void)n_in; (void)out_size; (void)ws_size;
}

// Round 20
// 282.456 us; speedup vs baseline: 1.2783x; 1.0268x over previous
//
#include <hip/hip_runtime.h>
#include <stdint.h>

typedef unsigned short u16;
typedef uint8_t u8;
typedef __attribute__((ext_vector_type(8))) short short8;
typedef __attribute__((ext_vector_type(4))) float f32x4;
typedef __attribute__((ext_vector_type(4))) int i32x4;

#define EPSF 1e-5f
#define LGKM0 asm volatile("s_waitcnt lgkmcnt(0)" ::: "memory")
#define VM0   asm volatile("s_waitcnt vmcnt(0)" ::: "memory")
#define BAR   __builtin_amdgcn_s_barrier()
#define GLL(src, dst) __builtin_amdgcn_global_load_lds(                     \
    (const __attribute__((address_space(1))) void*)(src),                   \
    (__attribute__((address_space(3))) void*)(dst), 16, 0, 0)

__device__ __forceinline__ u16 f2bf(float f) {
  uint32_t u = __float_as_uint(f);
  u += 0x7FFFu + ((u >> 16) & 1u);
  return (u16)(u >> 16);
}
__device__ __forceinline__ u8 sgn8(float y) {
  return y > 0.f ? (u8)1 : (y < 0.f ? (u8)0xFF : (u8)0);
}

// ---------------- BN1 stats (x is NCHW f32: 32,128,64,64) ----------------
__global__ void bn1_stage1(const float* __restrict__ x, float* __restrict__ p1) {
  int c = blockIdx.x >> 2, s = blockIdx.x & 3;
  int tid = threadIdx.x;
  float sum = 0.f, sq = 0.f;
  for (int n = s * 8; n < s * 8 + 8; ++n) {
    const f32x4* bp = (const f32x4*)(x + (((size_t)(n * 128 + c)) << 12));
    #pragma unroll 4
    for (int i = tid; i < 1024; i += 256) {
      f32x4 v = bp[i];
      sum += v[0] + v[1] + v[2] + v[3];
      sq  += v[0]*v[0] + v[1]*v[1] + v[2]*v[2] + v[3]*v[3];
    }
  }
  __shared__ float rs[256], rq[256];
  rs[tid] = sum; rq[tid] = sq; __syncthreads();
  for (int st = 128; st > 0; st >>= 1) {
    if (tid < st) { rs[tid] += rs[tid + st]; rq[tid] += rq[tid + st]; }
    __syncthreads();
  }
  if (tid == 0) { p1[blockIdx.x] = rs[0]; p1[512 + blockIdx.x] = rq[0]; }
}

__global__ void bn1_stage2(const float* __restrict__ p1, const float* __restrict__ g,
                           const float* __restrict__ b, float* __restrict__ sc,
                           float* __restrict__ off) {
  int c = threadIdx.x; // 128 threads
  float s = 0.f, q = 0.f;
  for (int k = 0; k < 4; ++k) { s += p1[c * 4 + k]; q += p1[512 + c * 4 + k]; }
  float mean = s * (1.f / 131072.f);
  float var  = q * (1.f / 131072.f) - mean * mean;
  float is = rsqrtf(var + EPSF);
  float scv = g[c] * is;
  sc[c] = scv;
  off[c] = b[c] - mean * scv;
}

// ---------------- BN2 stage2: reduce per-block partials [2048][256] ----------------
__global__ void bn2_stage2b(const float* __restrict__ pS, const float* __restrict__ pQ,
                            const float* __restrict__ g, const float* __restrict__ bb,
                            float* __restrict__ sc, float* __restrict__ off) {
  int o = blockIdx.x, t = threadIdx.x;
  __shared__ float rs[256], rq[256];
  float s = 0.f, q = 0.f;
  #pragma unroll
  for (int k = 0; k < 8; ++k) {
    size_t j = t + k * 256;
    s += pS[j * 256 + o];
    q += pQ[j * 256 + o];
  }
  rs[t] = s; rq[t] = q; __syncthreads();
  for (int st = 128; st > 0; st >>= 1) {
    if (t < st) { rs[t] += rs[t + st]; rq[t] += rq[t + st]; }
    __syncthreads();
  }
  if (t == 0) {
    float mean = rs[0] * (1.f / 131072.f);
    float var  = rq[0] * (1.f / 131072.f) - mean * mean;
    float is = rsqrtf(var + EPSF);
    float scv = g[o] * is;
    sc[o] = scv;
    off[o] = bb[o] - mean * scv;
  }
}

// ---------------- weight prep ----------------
__device__ __forceinline__ float blk_reduce(float v, float* red) {
  int t = threadIdx.x;
  red[t] = v; __syncthreads();
  for (int st = 128; st > 0; st >>= 1) {
    if (t < st) red[t] += red[t + st];
    __syncthreads();
  }
  float r = red[0]; __syncthreads();
  return r;
}

// i8 B pack, lane-major per 8 wave regions (32 output cols each):
// byte ((st*8 + rg8)*64 + (k>>4)*16 + (o&15))*32 + ((o>>4)&1)*16 + (k&15)
// holds sign(w[o][ch]) for step st, where rg8 = o>>5.
// A wave's lane (kq,li) reads its 2 B fragments as 32 contiguous bytes at
// region + lane*32.  conv1: st = cc*9+tap, ch = cc*64+k (18 steps).
// conv2: st = c4*9+tap, ch = c4*64+k (36 steps).
// skip bf16 lane-major per region: u16 ((e*8+rg8)*64 + kq*16+li)*32 + (ks*2+nf)*8 + j
// holds sign(wsk[o = rg8*32+nf*16+li][e*64 + ks*32 + kq*8 + j]) * ask/alpha2.
__global__ void prep_weights(const float* __restrict__ w1, const float* __restrict__ w2,
                             const float* __restrict__ wsk, u8* __restrict__ w1s,
                             u8* __restrict__ w2s, u16* __restrict__ wskr,
                             float* __restrict__ alpha1, float* __restrict__ alpha2) {
  int o = blockIdx.x, t = threadIdx.x;
  int rg8 = o >> 5;
  __shared__ float red[256];
  float s = 0.f;
  for (int j = t; j < 1152; j += 256) s += fabsf(w1[(size_t)o * 1152 + j]);
  float a1 = blk_reduce(s, red) * (1.f / 1152.f);
  if (t == 0) alpha1[o] = a1;
  for (int j = t; j < 1152; j += 256) {
    int st = j >> 6, k = j & 63;
    int cc = st / 9, tap = st % 9;
    int ch = cc * 64 + k;
    size_t idx = ((size_t)((st * 8 + rg8) * 64 + (k >> 4) * 16 + (o & 15))) * 32 +
                 ((o >> 4) & 1) * 16 + (k & 15);
    w1s[idx] = sgn8(w1[(size_t)o * 1152 + ch * 9 + tap]);
  }
  s = 0.f;
  for (int j = t; j < 2304; j += 256) s += fabsf(w2[(size_t)o * 2304 + j]);
  float a2 = blk_reduce(s, red) * (1.f / 2304.f);
  if (t == 0) alpha2[o] = a2;
  for (int j = t; j < 2304; j += 256) {
    int st = j >> 6, k = j & 63;
    int c4 = st / 9, tap = st % 9;
    int ch = c4 * 64 + k;
    size_t idx = ((size_t)((st * 8 + rg8) * 64 + (k >> 4) * 16 + (o & 15))) * 32 +
                 ((o >> 4) & 1) * 16 + (k & 15);
    w2s[idx] = sgn8(w2[(size_t)o * 2304 + ch * 9 + tap]);
  }
  s = 0.f;
  for (int j = t; j < 128; j += 256) s += fabsf(wsk[o * 128 + j]);
  float ask = blk_reduce(s, red) * (1.f / 128.f);
  float ratio = ask / a2;
  int nf = (o >> 4) & 1, li = o & 15;
  for (int j = t; j < 128; j += 256) {
    int e = j >> 6, c = j & 63;
    int ks = c >> 5, kq = (c >> 3) & 3, jj = c & 7;
    float w = wsk[o * 128 + j];
    float v = w > 0.f ? ratio : (w < 0.f ? -ratio : 0.f);
    wskr[((size_t)((e * 8 + rg8) * 64 + kq * 16 + li)) * 32 + (ks * 2 + nf) * 8 + jj] =
        f2bf(v);
  }
}

// ---------------- temb = t @ tw^T + tb ----------------
__global__ void temb_k(const float* __restrict__ t, const float* __restrict__ tw,
                       const float* __restrict__ tb, float* __restrict__ temb) {
  int bb = blockIdx.x, o = threadIdx.x;
  __shared__ float tl[512];
  tl[o] = t[bb * 512 + o];
  tl[o + 256] = t[bb * 512 + 256 + o];
  __syncthreads();
  float acc = tb[o];
  #pragma unroll 8
  for (int k = 0; k < 512; ++k) acc += tl[k] * tw[(size_t)o * 512 + k];
  temb[bb * 256 + o] = acc;
}

// ------- border zero: 192 i8 planes of [66][66][64], borders only -------
__global__ void border_zero(u8* __restrict__ Abuf) {
  u8* plane = Abuf + (size_t)blockIdx.x * 278784;
  int tid = threadIdx.x;
  i32x4 z = {};
  for (int idx = tid; idx < 260; idx += 256) {
    int row, px;
    if (idx < 66) { row = 0; px = idx; }
    else if (idx < 132) { row = 65; px = idx - 66; }
    else { int e = idx - 132; row = 1 + (e >> 1); px = (e & 1) * 65; }
    u8* p = plane + (size_t)(row * 66 + px) * 64;
    #pragma unroll
    for (int i = 0; i < 4; ++i) *(i32x4*)(p + i * 16) = z;
  }
}

// -------- binact1: x NCHW -> a1p i8 planes [b*2+cc][66][66][64] + xb bf16 [m][128] --------
__global__ void binact1(const float* __restrict__ x, const float* __restrict__ sc,
                        const float* __restrict__ off, u8* __restrict__ a1p,
                        u16* __restrict__ xb) {
  int b = blockIdx.x >> 6, y = blockIdx.x & 63, tid = threadIdx.x;
  __shared__ u8  ls[64 * 144];
  __shared__ u16 lx[64 * 136];
  int c = tid >> 1, x0 = (tid & 1) * 32;
  const float* src = x + (((size_t)(b * 128 + c)) << 12) + y * 64 + x0;
  float s0 = sc[c], o0 = off[c];
  #pragma unroll
  for (int i = 0; i < 32; i += 4) {
    f32x4 v = *(const f32x4*)(src + i);
    #pragma unroll
    for (int j = 0; j < 4; ++j) {
      int xc = x0 + i + j;
      float yv = s0 * v[j] + o0;
      ls[xc * 144 + c] = sgn8(yv);
      lx[xc * 136 + c] = f2bf(v[j]);
    }
  }
  __syncthreads();
  int xx = tid >> 2, cg = (tid & 3) * 32;
  int cc = cg >> 6, ch0 = cg & 63;
  u8*  pdst = a1p + ((size_t)(b * 2 + cc) * 4356 + (y + 1) * 66 + xx + 1) * 64 + ch0;
  u16* xdst = xb + ((size_t)blockIdx.x * 64 + xx) * 128 + cg;
  *(i32x4*)(pdst)      = *(const i32x4*)&ls[xx * 144 + cg];
  *(i32x4*)(pdst + 16) = *(const i32x4*)&ls[xx * 144 + cg + 16];
  #pragma unroll
  for (int i = 0; i < 32; i += 8)
    *(i32x4*)(xdst + i) = *(const i32x4*)&lx[xx * 136 + cg + i];
}

// -------- binact2: h [m][256] f32 -> a2p i8 planes [b*4+c4][66][66][64] --------
__global__ void binact2(const float* __restrict__ h, const float* __restrict__ sc,
                        const float* __restrict__ off, u8* __restrict__ a2p) {
  int b = blockIdx.x >> 6, y = blockIdx.x & 63, tid = threadIdx.x;
  __shared__ float s_sc[256], s_off[256];
  s_sc[tid] = sc[tid]; s_off[tid] = off[tid];
  __syncthreads();
  const f32x4* src = (const f32x4*)(h + (size_t)blockIdx.x * 16384);
  #pragma unroll 4
  for (int i = tid; i < 4096; i += 256) {
    f32x4 v = src[i];
    int px = i >> 6, c0 = (i & 63) * 4;
    int c4 = c0 >> 6, chm = c0 & 63;
    uint32_t p = (uint32_t)sgn8(s_sc[c0 + 0] * v[0] + s_off[c0 + 0]) |
                 ((uint32_t)sgn8(s_sc[c0 + 1] * v[1] + s_off[c0 + 1]) << 8) |
                 ((uint32_t)sgn8(s_sc[c0 + 2] * v[2] + s_off[c0 + 2]) << 16) |
                 ((uint32_t)sgn8(s_sc[c0 + 3] * v[3] + s_off[c0 + 3]) << 24);
    u8* dst = a2p + ((size_t)(b * 4 + c4) * 4356 + (y + 1) * 66 + px + 1) * 64 + chm;
    *(uint32_t*)dst = p;
  }
}

// ------- i8 implicit-GEMM conv: 8 waves, 32-col per wave, B in REGISTERS -------
// M=64 (1 image row), N=256, 512 thr = 8 waves, 16.9 KB LDS (window + scratch).
// A: [3][66][64ch] i8 window per chunk (pre-swizzled-source GLL), read-only.
// B: lane-major 32B/lane/step, coalesced global->reg loads, ping-pong named
//    arrays (bA/bB, rule #20), issued 2 steps ahead. NO manual waitcnts in
//    steady loop (compiler emits counted waits). acc[4][2] = 32 AGPRs; arch
//    regs ~64 -> 4 waves/SIMD without spill. Window drain per 9-step chunk.
template <int NCHUNK, bool SKIP, bool ADD_TEMB, bool STATS, bool DIRECT>
__global__ __launch_bounds__(512, 2) void convk(
    const u8* __restrict__ Apl, const u16* __restrict__ xb,
    const u8* __restrict__ wB, const u16* __restrict__ wskr,
    const float* __restrict__ alpha, const float* __restrict__ temb,
    float* __restrict__ outp, float* __restrict__ pS, float* __restrict__ pQ) {
  constexpr int NS = NCHUNK * 9;
  __shared__ u8 smem[16896];
  u8* lA = smem;            // 12672 B window; epilogue scratch reuses smem
  const int tid = threadIdx.x;
  const int lane = tid & 63, wn = tid >> 6;      // wn in 0..7
  const int kq = lane >> 4, li = lane & 15;

  const int bid = blockIdx.x;
  const int tile = (bid & 7) * 256 + (bid >> 3);   // XCD-chunked swizzle (2048%8==0)
  const int m0 = tile * 64;
  const int b = tile >> 6, y = tile & 63;

  // ---- B: lane-major register fragments, 2 steps deep ----
  const u8* wlane = wB + (size_t)wn * 2048 + (size_t)lane * 32;
  auto loadB = [&](int s, i32x4 (&dst)[2]) {
    const u8* src = wlane + (size_t)s * 16384;
    dst[0] = *(const i32x4*)src;
    dst[1] = *(const i32x4*)(src + 16);
  };

  // ---- A window: 792 granules, linear dest + pre-swizzled source ----
  auto winLoad = [&](int c) {
    const u8* gp = Apl + (size_t)(b * NCHUNK + c) * 278784 + (size_t)y * 4224;
    {
      int g = tid;
      int row = g / 264, rem = g - row * 264;
      int px = rem >> 2, sl = rem & 3;
      const u8* src = gp + (size_t)(row * 66 + px) * 64 + ((sl ^ ((px >> 1) & 3)) << 4);
      u8* dst = lA + (size_t)(tid & ~63) * 16;
      GLL(src, dst);
    }
    if (tid < 280) {
      int g = 512 + tid;
      int row = g / 264, rem = g - row * 264;
      int px = rem >> 2, sl = rem & 3;
      const u8* src = gp + (size_t)(row * 66 + px) * 64 + ((sl ^ ((px >> 1) & 3)) << 4);
      u8* dst = lA + (size_t)(512 + (tid & ~63)) * 16;
      GLL(src, dst);
    }
  };

  // ---- A fragment base pointers ----
  const u8* pA[3];
  #pragma unroll
  for (int dx = 0; dx < 3; ++dx)
    pA[dx] = lA + (li + dx) * 64 + ((kq ^ (((li + dx) >> 1) & 3)) << 4);

  i32x4 acc[4][2] = {};

  auto compute = [&](int tap, i32x4 (&bcur)[2]) {
    const int dy = tap / 3, dx = tap % 3;
    i32x4 av[4];
    #pragma unroll
    for (int f = 0; f < 4; ++f)
      av[f] = *(const i32x4*)(pA[dx] + dy * 4224 + f * 1024);
    __builtin_amdgcn_s_setprio(1);
    #pragma unroll
    for (int mf = 0; mf < 4; ++mf)
      #pragma unroll
      for (int nf = 0; nf < 2; ++nf)
        acc[mf][nf] = __builtin_amdgcn_mfma_i32_16x16x64_i8(
            av[mf], bcur[nf], acc[mf][nf], 0, 0, 0);
    __builtin_amdgcn_s_setprio(0);
  };

  // ---- prologue: window 0 + B(0), B(1) into regs ----
  winLoad(0);
  i32x4 bA[2], bB[2];
  loadB(0, bA);
  loadB(1, bB);
  VM0;                 // window + B regs landed
  BAR;                 // publish window

  // ---- main loop: no manual waits; window drain per 9-step chunk ----
  #pragma unroll
  for (int s = 0; s < NS; ++s) {
    if (NCHUNK > 1 && s > 0 && (s % 9) == 0) {
      LGKM0; BAR;               // all waves done reading old window
      winLoad(s / 9);
      VM0; BAR;                 // new window landed (drains B loads too, ok)
    }
    if ((s & 1) == 0) {
      compute(s % 9, bA);
      if (s + 2 < NS) loadB(s + 2, bA);
    } else {
      compute(s % 9, bB);
      if (s + 2 < NS) loadB(s + 2, bB);
    }
  }

  f32x4 facc[4][2];
  if constexpr (SKIP) {
    #pragma unroll
    for (int mf = 0; mf < 4; ++mf)
      #pragma unroll
      for (int nf = 0; nf < 2; ++nf)
        #pragma unroll
        for (int r = 0; r < 4; ++r)
          facc[mf][nf][r] = (float)acc[mf][nf][r];
    const u8* pAs[2];
    #pragma unroll
    for (int ks = 0; ks < 2; ++ks)
      pAs[ks] = lA + li * 128 + ((((ks << 2) + kq) ^ (li & 7)) << 4);
    LGKM0; BAR;                   // lA free to overwrite
    #pragma unroll
    for (int e = 0; e < 2; ++e) {
      // stage skip-A (xb e-half, pre-swizzled source) into lA: 512 granules
      {
        int g = tid;
        int m = g >> 3, sl = g & 7;
        const u8* src = (const u8*)xb + (size_t)(m0 + m) * 256 + e * 128 +
                        ((sl ^ (m & 7)) << 4);
        u8* dst = lA + (size_t)(tid & ~63) * 16;
        GLL(src, dst);
      }
      // skip-B lane-major fragments -> regs (4 x short8 per lane)
      const u16* bbase = wskr + ((size_t)((e * 8 + wn) * 64) + lane) * 32;
      short8 sb[4];
      #pragma unroll
      for (int i = 0; i < 4; ++i) sb[i] = *(const short8*)(bbase + i * 8);
      VM0; BAR;
      #pragma unroll
      for (int ks = 0; ks < 2; ++ks) {
        short8 av[4];
        #pragma unroll
        for (int f = 0; f < 4; ++f) av[f] = *(const short8*)(pAs[ks] + f * 2048);
        __builtin_amdgcn_s_setprio(1);
        #pragma unroll
        for (int mf = 0; mf < 4; ++mf)
          #pragma unroll
          for (int nf = 0; nf < 2; ++nf)
            facc[mf][nf] = __builtin_amdgcn_mfma_f32_16x16x32_bf16(
                av[mf], sb[ks * 2 + nf], facc[mf][nf], 0, 0, 0);
        __builtin_amdgcn_s_setprio(0);
      }
      if (e == 0) { LGKM0; BAR; }
    }
  }

  const int cb = wn * 32 + li;

  if constexpr (STATS) {
    float als[2], tas[2];
    #pragma unroll
    for (int nf = 0; nf < 2; ++nf) {
      int o = cb + nf * 16;
      als[nf] = alpha[o];
      tas[nf] = ADD_TEMB ? temb[b * 256 + o] : 0.f;
    }
    // per-block BN2 partials (deterministic; contiguous [bid][256])
    float ps[2] = {0.f, 0.f}, pq[2] = {0.f, 0.f};
    #pragma unroll
    for (int nf = 0; nf < 2; ++nf)
      #pragma unroll
      for (int mf = 0; mf < 4; ++mf)
        #pragma unroll
        for (int r = 0; r < 4; ++r) {
          float v = (float)acc[mf][nf][r] * als[nf] + tas[nf];
          ps[nf] += v; pq[nf] += v * v;
        }
    #pragma unroll
    for (int nf = 0; nf < 2; ++nf) {
      ps[nf] += __shfl_xor(ps[nf], 16); ps[nf] += __shfl_xor(ps[nf], 32);
      pq[nf] += __shfl_xor(pq[nf], 16); pq[nf] += __shfl_xor(pq[nf], 32);
    }
    if (lane < 16) {
      #pragma unroll
      for (int nf = 0; nf < 2; ++nf) {
        pS[(size_t)bid * 256 + wn * 32 + nf * 16 + lane] = ps[nf];
        pQ[(size_t)bid * 256 + wn * 32 + nf * 16 + lane] = pq[nf];
      }
    }
    __syncthreads();      // all waves done with window before reuse as scratch
    // restage h tile through LDS in four 16-row passes [16][256] f32 (16 KB).
    // FULLY UNROLLED (rule #20): pass p == mf.
    float* ld = (float*)smem;
    const int c3 = li & 3;
    #pragma unroll
    for (int p = 0; p < 4; ++p) {
      #pragma unroll
      for (int nf = 0; nf < 2; ++nf) {
        int colg0 = (cb >> 2) + nf * 4;
        #pragma unroll
        for (int r = 0; r < 4; ++r) {
          int rloc = 4 * kq + r;
          float v = (float)acc[p][nf][r] * als[nf] + tas[nf];
          ld[rloc * 256 + ((colg0 ^ kq) << 2) + c3] = v;
        }
      }
      __syncthreads();
      #pragma unroll
      for (int it = 0; it < 2; ++it) {
        int flat = tid + it * 512;
        int row = flat >> 6, c4 = flat & 63;
        int c4p = c4 ^ ((row >> 2) & 3);
        f32x4 v = *(const f32x4*)&ld[row * 256 + c4p * 4];
        *(f32x4*)(outp + (size_t)(m0 + p * 16 + row) * 256 + c4 * 4) = v;
      }
      __syncthreads();
    }
  } else if constexpr (DIRECT) {
    // NCHW transpose epilogue: [64 m][65] f32 tile per 64-ch quarter.
    // Quarter c4 is written by waves 2*c4 and 2*c4+1 (32 cols each).
    float* tb2 = (float*)smem;
    float* obase = outp + (((size_t)(b * 256)) << 12) + (m0 & 4095);
    __syncthreads();
    #pragma unroll
    for (int c4 = 0; c4 < 4; ++c4) {
      if ((wn >> 1) == c4) {
        #pragma unroll
        for (int nf = 0; nf < 2; ++nf) {
          int cq = (wn & 1) * 32 + nf * 16 + li;
          float al = alpha[c4 * 64 + cq];
          #pragma unroll
          for (int mf = 0; mf < 4; ++mf) {
            int cs = cq ^ ((mf >> 1) & 3);
            #pragma unroll
            for (int r = 0; r < 4; ++r)
              tb2[(mf * 16 + 4 * kq + r) * 65 + cs] = facc[mf][nf][r] * al;
          }
        }
      }
      __syncthreads();
      #pragma unroll
      for (int it = 0; it < 2; ++it) {
        int flat = tid + it * 512;
        int ch = flat >> 4, mg = flat & 15;
        int chs = ch ^ ((mg >> 3) & 3);
        f32x4 v;
        #pragma unroll
        for (int e = 0; e < 4; ++e) v[e] = tb2[(mg * 4 + e) * 65 + chs];
        *(f32x4*)(obase + (((size_t)(c4 * 64 + ch)) << 12) + mg * 4) = v;
      }
      __syncthreads();
    }
  }
}

extern "C" void kernel_launch(void* const* d_in, const int* in_sizes, int n_in,
                              void* d_out, int out_size, void* d_ws, size_t ws_size,
                              hipStream_t stream) {
  const float* x      = (const float*)d_in[0];
  const float* t      = (const float*)d_in[1];
  const float* w1     = (const float*)d_in[2];
  const float* w2     = (const float*)d_in[3];
  const float* wskip  = (const float*)d_in[4];
  const float* gamma1 = (const float*)d_in[5];
  const float* beta1  = (const float*)d_in[6];
  const float* gamma2 = (const float*)d_in[7];
  const float* beta2  = (const float*)d_in[8];
  const float* tw     = (const float*)d_in[9];
  const float* tb     = (const float*)d_in[10];
  float* out = (float*)d_out;

  uint8_t* base = (uint8_t*)d_ws;
  size_t off = 0;
  auto alloc = [&](size_t bytes) {
    void* p = base + off;
    off += (bytes + 255) & ~(size_t)255;
    return p;
  };
  // 192 i8 planes of [66][66][64]: first 64 = a1p (32b x 2), next 128 = a2p (32b x 4)
  u8* Abuf     = (u8*)alloc((size_t)192 * 278784);
  u8* a1p      = Abuf;
  u8* a2p      = Abuf + (size_t)64 * 278784;
  u16* xb      = (u16*)alloc((size_t)131072 * 128 * 2);
  float* h     = (float*)alloc((size_t)131072 * 256 * 4);
  u8* w1s      = (u8*)alloc((size_t)18 * 16384);
  u8* w2s      = (u8*)alloc((size_t)36 * 16384);
  u16* wskr    = (u16*)alloc((size_t)2 * 8 * 4096);
  float* temb  = (float*)alloc(32 * 256 * 4);
  float* alpha1 = (float*)alloc(256 * 4);
  float* alpha2 = (float*)alloc(256 * 4);
  float* p1    = (float*)alloc(1024 * 4);
  float* pS    = (float*)alloc((size_t)2048 * 256 * 4);
  float* pQ    = (float*)alloc((size_t)2048 * 256 * 4);
  float* sc1   = (float*)alloc(128 * 4);
  float* off1  = (float*)alloc(128 * 4);
  float* sc2   = (float*)alloc(256 * 4);
  float* off2  = (float*)alloc(256 * 4);

  border_zero<<<192, 256, 0, stream>>>(Abuf);

  bn1_stage1<<<512, 256, 0, stream>>>(x, p1);
  bn1_stage2<<<1, 128, 0, stream>>>(p1, gamma1, beta1, sc1, off1);
  prep_weights<<<256, 256, 0, stream>>>(w1, w2, wskip, w1s, w2s, wskr, alpha1, alpha2);
  temb_k<<<32, 256, 0, stream>>>(t, tw, tb, temb);
  binact1<<<2048, 256, 0, stream>>>(x, sc1, off1, a1p, xb);

  // conv1: i8, 2 chunks, writes h + BN2 per-block partials
  convk<2, false, true, true, false><<<2048, 512, 0, stream>>>(
      a1p, xb, w1s, (const u16*)nullptr, alpha1, temb, h, pS, pQ);

  bn2_stage2b<<<256, 256, 0, stream>>>(pS, pQ, gamma2, beta2, sc2, off2);
  binact2<<<2048, 256, 0, stream>>>(h, sc2, off2, a2p);

  // conv2: i8, 4 chunks + bf16 skip tail, direct NCHW output
  convk<4, true, false, false, true><<<2048, 512, 0, stream>>>(
      a2p, xb, w2s, wskr, alpha2, (const float*)nullptr, out,
      (float*)nullptr, (float*)nullptr);

  (void)in_sizes; (void)n_in; (void)out_size; (void)ws_size;
}